// Round 1
// baseline (306.588 us; speedup 1.0000x reference)
//
#include <hip/hip_runtime.h>

#define NN 65536
#define DD 8
#define LATD 64
#define HIDD 128
#define FEATD 16
#define TILE 64

// ---------------- Kernel 1: per-entry argmax over D + per-decoder counts ----
__global__ __launch_bounds__(256) void k_argmax_count(const float* __restrict__ ap,
                                                      int* __restrict__ idx,
                                                      int* __restrict__ counts) {
  __shared__ int bc[DD];
  int t = threadIdx.x;
  if (t < DD) bc[t] = 0;
  __syncthreads();
  int n = blockIdx.x * 256 + t;
  float best = ap[n];
  int bd = 0;
#pragma unroll
  for (int d = 1; d < DD; ++d) {
    float v = ap[d * NN + n];
    if (v > best) { best = v; bd = d; }  // strict > keeps FIRST max (jnp.argmax)
  }
  idx[n] = bd;
  atomicAdd(&bc[bd], 1);
  __syncthreads();
  if (t < DD) atomicAdd(&counts[t], bc[t]);
}

// ---------------- Kernel 2: 8-element exclusive prefix ---------------------
__global__ void k_prefix(const int* __restrict__ counts, int* __restrict__ offsets) {
  int s = 0;
#pragma unroll
  for (int d = 0; d < DD; ++d) { offsets[d] = s; s += counts[d]; }
}

// ---------------- Kernel 3: scatter entries into per-decoder lists ---------
__global__ __launch_bounds__(256) void k_scatter(const int* __restrict__ idx,
                                                 const int* __restrict__ offsets,
                                                 int* __restrict__ cursor,
                                                 int* __restrict__ perm) {
  __shared__ int bc[DD];
  __shared__ int bbase[DD];
  int t = threadIdx.x;
  if (t < DD) bc[t] = 0;
  __syncthreads();
  int n = blockIdx.x * 256 + t;
  int myd = idx[n];
  int lr = atomicAdd(&bc[myd], 1);
  __syncthreads();
  if (t < DD) bbase[t] = atomicAdd(&cursor[t], bc[t]);
  __syncthreads();
  perm[offsets[myd] + bbase[myd] + lr] = n;
}

// ---------------- Kernel 4: fused 3-layer MLP per decoder bucket -----------
// block = 256 threads (4 waves), TILE=64 entries; lane = entry row.
// Waves split the output dim: layers 1&2 -> 32 outputs/wave (2 groups of 16),
// layer 3 -> 4 outputs/wave. Scale rows are wave-uniform float4 loads (L1
// broadcast). LDS strides 65/129 give (l+k)%32 banks -> 2-way (free).
__global__ __launch_bounds__(256) void k_mlp(
    const float* __restrict__ weight, const float* __restrict__ divv,
    const float* __restrict__ scale0, const float* __restrict__ shift0,
    const float* __restrict__ scale1, const float* __restrict__ shift1,
    const float* __restrict__ scale2, const float* __restrict__ shift2,
    const int* __restrict__ counts, const int* __restrict__ offsets,
    const int* __restrict__ perm, float* __restrict__ out) {
  int d = blockIdx.x >> 10;          // 1024 tiles per decoder
  int tile = blockIdx.x & 1023;
  int cnt = counts[d];
  int base = tile * TILE;
  if (base >= cnt) return;
  int off = offsets[d];
  int nvalid = min(TILE, cnt - base);

  __shared__ float sA[TILE * 129];   // H1 (stride 129)
  __shared__ float sB[TILE * 129];   // X (stride 65), later reused for H2 (stride 129)

  int t = threadIdx.x;
  // ---- stage X = rint(weight)/div, gathered via perm, coalesced over i ----
#pragma unroll
  for (int rep = 0; rep < 16; ++rep) {
    int lin = rep * 256 + t;
    int r = lin >> 6, i = lin & 63;
    float v = 0.f;
    if (r < nvalid) {
      int e = perm[off + base + r];
      v = rintf(weight[e * LATD + i]) / divv[i];
    }
    sB[r * 65 + i] = v;
  }
  __syncthreads();

  int w = t >> 6, l = t & 63;

  // ---- layer 1: [64] -> [128], relu ----
  {
    const float* S = scale0 + d * (LATD * HIDD);
    const float* sh = shift0 + d * HIDD;
#pragma unroll
    for (int g = 0; g < 2; ++g) {
      int o0 = w * 32 + g * 16;
      float acc[16];
#pragma unroll
      for (int j = 0; j < 16; ++j) acc[j] = sh[o0 + j];
#pragma unroll 2
      for (int k = 0; k < LATD; ++k) {
        float xv = sB[l * 65 + k];
        const float4* sp = (const float4*)(S + k * HIDD + o0);
#pragma unroll
        for (int jq = 0; jq < 4; ++jq) {
          float4 sv = sp[jq];
          acc[jq * 4 + 0] = fmaf(xv, sv.x, acc[jq * 4 + 0]);
          acc[jq * 4 + 1] = fmaf(xv, sv.y, acc[jq * 4 + 1]);
          acc[jq * 4 + 2] = fmaf(xv, sv.z, acc[jq * 4 + 2]);
          acc[jq * 4 + 3] = fmaf(xv, sv.w, acc[jq * 4 + 3]);
        }
      }
#pragma unroll
      for (int j = 0; j < 16; ++j) sA[l * 129 + o0 + j] = fmaxf(acc[j], 0.f);
    }
  }
  __syncthreads();

  // ---- layer 2: [128] -> [128], relu (reads sA, writes H2 into sB) ----
  {
    const float* S = scale1 + d * (HIDD * HIDD);
    const float* sh = shift1 + d * HIDD;
#pragma unroll
    for (int g = 0; g < 2; ++g) {
      int o0 = w * 32 + g * 16;
      float acc[16];
#pragma unroll
      for (int j = 0; j < 16; ++j) acc[j] = sh[o0 + j];
#pragma unroll 2
      for (int k = 0; k < HIDD; ++k) {
        float xv = sA[l * 129 + k];
        const float4* sp = (const float4*)(S + k * HIDD + o0);
#pragma unroll
        for (int jq = 0; jq < 4; ++jq) {
          float4 sv = sp[jq];
          acc[jq * 4 + 0] = fmaf(xv, sv.x, acc[jq * 4 + 0]);
          acc[jq * 4 + 1] = fmaf(xv, sv.y, acc[jq * 4 + 1]);
          acc[jq * 4 + 2] = fmaf(xv, sv.z, acc[jq * 4 + 2]);
          acc[jq * 4 + 3] = fmaf(xv, sv.w, acc[jq * 4 + 3]);
        }
      }
#pragma unroll
      for (int j = 0; j < 16; ++j) sB[l * 129 + o0 + j] = fmaxf(acc[j], 0.f);
    }
  }
  __syncthreads();

  // ---- layer 3: [128] -> [16], no activation ----
  {
    const float* S = scale2 + d * (HIDD * FEATD);
    const float* sh = shift2 + d * FEATD;
    int o0 = w * 4;
    float a0 = sh[o0 + 0], a1 = sh[o0 + 1], a2 = sh[o0 + 2], a3 = sh[o0 + 3];
#pragma unroll 4
    for (int k = 0; k < HIDD; ++k) {
      float xv = sB[l * 129 + k];
      float4 sv = *(const float4*)(S + k * FEATD + o0);
      a0 = fmaf(xv, sv.x, a0);
      a1 = fmaf(xv, sv.y, a1);
      a2 = fmaf(xv, sv.z, a2);
      a3 = fmaf(xv, sv.w, a3);
    }
    if (l < nvalid) {
      int e = perm[off + base + l];
      *(float4*)(out + e * FEATD + o0) = make_float4(a0, a1, a2, a3);
    }
  }
}

// ---------------------------------------------------------------------------
extern "C" void kernel_launch(void* const* d_in, const int* in_sizes, int n_in,
                              void* d_out, int out_size, void* d_ws, size_t ws_size,
                              hipStream_t stream) {
  const float* weight      = (const float*)d_in[0];  // [N, 64]
  const float* alpha_param = (const float*)d_in[1];  // [8, N]
  const float* divv        = (const float*)d_in[2];  // [64]
  const float* scale0      = (const float*)d_in[3];  // [8, 64, 128]
  const float* shift0      = (const float*)d_in[4];  // [8, 1, 128]
  const float* scale1      = (const float*)d_in[5];  // [8, 128, 128]
  const float* shift1      = (const float*)d_in[6];  // [8, 1, 128]
  const float* scale2      = (const float*)d_in[7];  // [8, 128, 16]
  const float* shift2      = (const float*)d_in[8];  // [8, 1, 16]
  float* out = (float*)d_out;

  int* ws      = (int*)d_ws;
  int* counts  = ws;           // [8]
  int* offsets = ws + 8;       // [8]
  int* cursor  = ws + 16;      // [8]
  int* idx     = ws + 32;      // [N]
  int* perm    = ws + 32 + NN; // [N]

  hipMemsetAsync(ws, 0, 24 * sizeof(int), stream);
  k_argmax_count<<<NN / 256, 256, 0, stream>>>(alpha_param, idx, counts);
  k_prefix<<<1, 1, 0, stream>>>(counts, offsets);
  k_scatter<<<NN / 256, 256, 0, stream>>>(idx, offsets, cursor, perm);
  k_mlp<<<DD * (NN / TILE), 256, 0, stream>>>(weight, divv, scale0, shift0,
                                              scale1, shift1, scale2, shift2,
                                              counts, offsets, perm, out);
}

// Round 2
// 36.508 us; speedup vs baseline: 8.3979x; 8.3979x over previous
//
#include <hip/hip_runtime.h>

#define NN 65536
#define DD 8
#define LATD 64
#define HIDD 128
#define FEATD 16
#define BPD 64            // k_mlp blocks per decoder
#define STRH 136          // sH / s1T / s2T stride (ushorts): 272 B = 17*16 (odd quad stride)
#define STRS0 72          // s0T stride: 144 B = 9*16 (odd quad stride)

typedef __attribute__((ext_vector_type(8))) short short8;
typedef __attribute__((ext_vector_type(4))) float f32x4;
typedef __attribute__((ext_vector_type(8))) unsigned short ushort8;

static __device__ __forceinline__ unsigned short f2bf(float f) {
  union { float f; unsigned u; } v; v.f = f;
  unsigned r = v.u + 0x7FFFu + ((v.u >> 16) & 1u);  // RNE; exact for small ints
  return (unsigned short)(r >> 16);
}

// ---- bucket: argmax over D + scatter into per-decoder perm lists ----------
__global__ __launch_bounds__(256) void k_bucket(const float* __restrict__ ap,
                                                int* __restrict__ cursor,
                                                unsigned short* __restrict__ perm) {
  __shared__ int bc[DD];
  __shared__ int bbase[DD];
  int t = threadIdx.x;
  if (t < DD) bc[t] = 0;
  __syncthreads();
  int n = blockIdx.x * 256 + t;
  float best = ap[n];
  int bd = 0;
#pragma unroll
  for (int d = 1; d < DD; ++d) {
    float v = ap[d * NN + n];
    if (v > best) { best = v; bd = d; }  // strict >: first max (jnp.argmax)
  }
  int lr = atomicAdd(&bc[bd], 1);
  __syncthreads();
  if (t < DD) bbase[t] = atomicAdd(&cursor[t], bc[t]);
  __syncthreads();
  perm[bd * NN + bbase[bd] + lr] = (unsigned short)n;
}

// ---- convert scales to bf16, transposed to [d][n][k] ----------------------
__global__ __launch_bounds__(256) void k_convert(const float* __restrict__ s0,
                                                 const float* __restrict__ s1,
                                                 const float* __restrict__ s2,
                                                 unsigned short* __restrict__ g0,
                                                 unsigned short* __restrict__ g1,
                                                 unsigned short* __restrict__ g2) {
  int o = blockIdx.x * 256 + threadIdx.x;
  if (o < DD * HIDD * LATD) {            // g0[d][n(128)][k(64)] <- s0[d][k][n]
    int d = o >> 13, rem = o & 8191, n = rem >> 6, k = rem & 63;
    g0[o] = f2bf(s0[d * 8192 + k * 128 + n]);
  }
  if (o < DD * HIDD * HIDD) {            // g1[d][n(128)][k(128)] <- s1[d][k][n]
    int d = o >> 14, rem = o & 16383, n = rem >> 7, k = rem & 127;
    g1[o] = f2bf(s1[d * 16384 + k * 128 + n]);
  }
  if (o < DD * FEATD * HIDD) {           // g2[d][n(16)][k(128)] <- s2[d][k][n]
    int d = o >> 11, rem = o & 2047, n = rem >> 7, k = rem & 127;
    g2[o] = f2bf(s2[d * 2048 + k * 16 + n]);
  }
}

// ---- fused 3-layer MLP on MFMA -------------------------------------------
// 256 thr = 4 waves; tile = 64 entries; wave w owns rows [16w,16w+16).
// Scales staged in LDS once per block; sH strips are wave-private -> no
// barriers in the tile loop.
__global__ __launch_bounds__(256, 2) void k_mlp(
    const float* __restrict__ weight, const float* __restrict__ divv,
    const float* __restrict__ shift0, const float* __restrict__ shift1,
    const float* __restrict__ shift2,
    const int* __restrict__ cursor, const unsigned short* __restrict__ perm,
    const unsigned short* __restrict__ g0, const unsigned short* __restrict__ g1,
    const unsigned short* __restrict__ g2,
    float* __restrict__ out) {
  __shared__ unsigned short sH[64 * STRH];     // H1/H2 strips (wave-private rows)
  __shared__ unsigned short s0T[128 * STRS0];  // scale0^T [n][k=64]
  __shared__ unsigned short s1T[128 * STRH];   // scale1^T [n][k=128]
  __shared__ unsigned short s2T[16 * STRH];    // scale2^T [n][k=128]

  int d = blockIdx.x / BPD;
  int bslot = blockIdx.x % BPD;
  int cnt = cursor[d];
  int t = threadIdx.x;
  int w = t >> 6, l = t & 63;
  int lrow = l & 15, kgrp = l >> 4;

  // ---- stage transposed bf16 scales once per block ----
  {
    const ushort8* src0 = (const ushort8*)(g0 + d * (HIDD * LATD));
#pragma unroll
    for (int c = 0; c < 4; ++c) {
      int lin = c * 256 + t, r = lin >> 3, wi = lin & 7;
      *(ushort8*)&s0T[r * STRS0 + wi * 8] = src0[lin];
    }
    const ushort8* src1 = (const ushort8*)(g1 + d * (HIDD * HIDD));
#pragma unroll
    for (int c = 0; c < 8; ++c) {
      int lin = c * 256 + t, r = lin >> 4, wi = lin & 15;
      *(ushort8*)&s1T[r * STRH + wi * 8] = src1[lin];
    }
    const ushort8* src2 = (const ushort8*)(g2 + d * (FEATD * HIDD));
    {
      int r = t >> 4, wi = t & 15;
      *(ushort8*)&s2T[r * STRH + wi * 8] = src2[t];
    }
  }
  __syncthreads();

  float sh2v = shift2[d * FEATD + lrow];

  for (int tile = bslot; tile * 64 < cnt; tile += BPD) {
    int base = tile * 64;
    int nvalid = min(64, cnt - base);

    // ---- L1 A-frags straight from global: x = rint(weight)/div, bf16 ----
    int arow = base + w * 16 + lrow;
    short8 xa[2];
#pragma unroll
    for (int s = 0; s < 2; ++s) {
      short8 v;
      if (arow < cnt) {
        int e = (int)perm[d * NN + arow];
        const float* wr = weight + e * LATD + s * 32 + kgrp * 8;
        const float* dv = divv + s * 32 + kgrp * 8;
        float4 f0 = *(const float4*)wr;
        float4 f1 = *(const float4*)(wr + 4);
        float4 q0 = *(const float4*)dv;
        float4 q1 = *(const float4*)(dv + 4);
        v[0] = (short)f2bf(rintf(f0.x) / q0.x);
        v[1] = (short)f2bf(rintf(f0.y) / q0.y);
        v[2] = (short)f2bf(rintf(f0.z) / q0.z);
        v[3] = (short)f2bf(rintf(f0.w) / q0.w);
        v[4] = (short)f2bf(rintf(f1.x) / q1.x);
        v[5] = (short)f2bf(rintf(f1.y) / q1.y);
        v[6] = (short)f2bf(rintf(f1.z) / q1.z);
        v[7] = (short)f2bf(rintf(f1.w) / q1.w);
      } else {
#pragma unroll
        for (int j = 0; j < 8; ++j) v[j] = 0;
      }
      xa[s] = v;
    }

    // ---- layer 1: [64]->[128], relu, write own sH strip ----
#pragma unroll
    for (int tt = 0; tt < 8; ++tt) {
      float sh = shift0[d * HIDD + tt * 16 + lrow];
      f32x4 acc = {sh, sh, sh, sh};
      short8 b0 = *(short8*)&s0T[(tt * 16 + lrow) * STRS0 + kgrp * 8];
      short8 b1 = *(short8*)&s0T[(tt * 16 + lrow) * STRS0 + 32 + kgrp * 8];
      acc = __builtin_amdgcn_mfma_f32_16x16x32_bf16(xa[0], b0, acc, 0, 0, 0);
      acc = __builtin_amdgcn_mfma_f32_16x16x32_bf16(xa[1], b1, acc, 0, 0, 0);
#pragma unroll
      for (int r = 0; r < 4; ++r)
        sH[(w * 16 + kgrp * 4 + r) * STRH + tt * 16 + lrow] = f2bf(fmaxf(acc[r], 0.f));
    }

    // ---- layer 2: [128]->[128], relu (A-frags to regs, write H2 in place) ----
    short8 ha[4];
#pragma unroll
    for (int s = 0; s < 4; ++s)
      ha[s] = *(short8*)&sH[(w * 16 + lrow) * STRH + s * 32 + kgrp * 8];
#pragma unroll
    for (int tt = 0; tt < 8; ++tt) {
      float sh = shift1[d * HIDD + tt * 16 + lrow];
      f32x4 acc = {sh, sh, sh, sh};
#pragma unroll
      for (int s = 0; s < 4; ++s) {
        short8 b = *(short8*)&s1T[(tt * 16 + lrow) * STRH + s * 32 + kgrp * 8];
        acc = __builtin_amdgcn_mfma_f32_16x16x32_bf16(ha[s], b, acc, 0, 0, 0);
      }
#pragma unroll
      for (int r = 0; r < 4; ++r)
        sH[(w * 16 + kgrp * 4 + r) * STRH + tt * 16 + lrow] = f2bf(fmaxf(acc[r], 0.f));
    }

    // ---- layer 3: [128]->[16], store via perm ----
    short8 ga[4];
#pragma unroll
    for (int s = 0; s < 4; ++s)
      ga[s] = *(short8*)&sH[(w * 16 + lrow) * STRH + s * 32 + kgrp * 8];
    f32x4 acc = {sh2v, sh2v, sh2v, sh2v};
#pragma unroll
    for (int s = 0; s < 4; ++s) {
      short8 b = *(short8*)&s2T[lrow * STRH + s * 32 + kgrp * 8];
      acc = __builtin_amdgcn_mfma_f32_16x16x32_bf16(ga[s], b, acc, 0, 0, 0);
    }
#pragma unroll
    for (int r = 0; r < 4; ++r) {
      int p = base + w * 16 + kgrp * 4 + r;
      if (p < cnt) {
        int e = (int)perm[d * NN + p];
        out[e * FEATD + lrow] = acc[r];
      }
    }
    (void)nvalid;
  }
}

// ---------------------------------------------------------------------------
extern "C" void kernel_launch(void* const* d_in, const int* in_sizes, int n_in,
                              void* d_out, int out_size, void* d_ws, size_t ws_size,
                              hipStream_t stream) {
  const float* weight      = (const float*)d_in[0];
  const float* alpha_param = (const float*)d_in[1];
  const float* divv        = (const float*)d_in[2];
  const float* scale0      = (const float*)d_in[3];
  const float* shift0      = (const float*)d_in[4];
  const float* scale1      = (const float*)d_in[5];
  const float* shift1      = (const float*)d_in[6];
  const float* scale2      = (const float*)d_in[7];
  const float* shift2      = (const float*)d_in[8];
  float* out = (float*)d_out;

  int* cursor = (int*)d_ws;                                   // [8]
  unsigned short* perm = (unsigned short*)((int*)d_ws + 8);   // [8][N]
  unsigned short* g0 = perm + DD * NN;                        // [8][128][64]
  unsigned short* g1 = g0 + DD * HIDD * LATD;                 // [8][128][128]
  unsigned short* g2 = g1 + DD * HIDD * HIDD;                 // [8][16][128]

  hipMemsetAsync(cursor, 0, DD * sizeof(int), stream);
  k_bucket<<<NN / 256, 256, 0, stream>>>(alpha_param, cursor, perm);
  k_convert<<<(DD * HIDD * HIDD) / 256, 256, 0, stream>>>(scale0, scale1, scale2, g0, g1, g2);
  k_mlp<<<DD * BPD, 256, 0, stream>>>(weight, divv, shift0, shift1, shift2,
                                      cursor, perm, g0, g1, g2, out);
}

// Round 3
// 30.337 us; speedup vs baseline: 10.1062x; 1.2034x over previous
//
#include <hip/hip_runtime.h>

#define NN 65536
#define DD 8
#define LATD 64
#define HIDD 128
#define FEATD 16
#define BPD 96            // k_mlp blocks per decoder (768 total = 3/CU)
#define SXS 72            // sX stride (u16): 144 B = 9 quads (odd -> conflict-free)
#define SHS 136           // sH stride (u16): 272 B = 17 quads (odd -> conflict-free)

typedef __attribute__((ext_vector_type(8))) short short8;
typedef __attribute__((ext_vector_type(4))) float f32x4;

static __device__ __forceinline__ unsigned short f2bf(float f) {
  union { float f; unsigned u; } v; v.f = f;
  unsigned r = v.u + 0x7FFFu + ((v.u >> 16) & 1u);  // RNE; exact for small ints
  return (unsigned short)(r >> 16);
}

// ---- bucket: argmax over D + scatter into per-decoder perm lists ----------
__global__ __launch_bounds__(256) void k_bucket(const float* __restrict__ ap,
                                                int* __restrict__ cursor,
                                                unsigned short* __restrict__ perm) {
  __shared__ int bc[DD];
  __shared__ int bbase[DD];
  int t = threadIdx.x;
  if (t < DD) bc[t] = 0;
  __syncthreads();
  int n = blockIdx.x * 256 + t;
  float best = ap[n];
  int bd = 0;
#pragma unroll
  for (int d = 1; d < DD; ++d) {
    float v = ap[d * NN + n];
    if (v > best) { best = v; bd = d; }  // strict >: first max (jnp.argmax)
  }
  int lr = atomicAdd(&bc[bd], 1);
  __syncthreads();
  if (t < DD) bbase[t] = atomicAdd(&cursor[t], bc[t]);
  __syncthreads();
  perm[bd * NN + bbase[bd] + lr] = (unsigned short)n;
}

// ---- fused 3-layer MLP: B-fragments in registers, H through LDS -----------
// 256 thr = 4 waves; tile = 64 entries. Wave w owns output col-blocks
// {2w, 2w+1} (16 cols each) for L1/L2; L3 row-group rg = w.
__global__ __launch_bounds__(256, 3) void k_mlp(
    const float* __restrict__ weight, const float* __restrict__ divv,
    const float* __restrict__ s0, const float* __restrict__ sh0,
    const float* __restrict__ s1, const float* __restrict__ sh1,
    const float* __restrict__ s2, const float* __restrict__ sh2,
    const int* __restrict__ cursor, const unsigned short* __restrict__ perm,
    float* __restrict__ out) {
  __shared__ unsigned short sX[64 * SXS];   // X  [entry][k=64] bf16
  __shared__ unsigned short sH1[64 * SHS];  // H1 [entry][k=128] bf16
  __shared__ unsigned short sH2[64 * SHS];  // H2 [entry][k=128] bf16
  __shared__ unsigned short sP[64];         // perm cache for this tile

  int d = blockIdx.x / BPD, bslot = blockIdx.x % BPD;
  int cnt = cursor[d];
  int t = threadIdx.x;
  int w = t >> 6, l = t & 63;
  int lrow = l & 15, kgrp = l >> 4;

  // ---- load B fragments (fp32 global -> bf16 regs), once per block ----
  short8 b0[2][2];  // [cb][ks] layer1 (k=64)
  short8 b1[2][4];  // [cb][ks] layer2 (k=128)
  short8 b2[4];     // [ks]     layer3 (k=128, 16 cols)
  float sh0v[2], sh1v[2];
  const float* S0 = s0 + d * LATD * HIDD;
  const float* S1 = s1 + d * HIDD * HIDD;
  const float* S2 = s2 + d * HIDD * FEATD;
#pragma unroll
  for (int cb = 0; cb < 2; ++cb) {
    int n = (2 * w + cb) * 16 + lrow;
#pragma unroll
    for (int ks = 0; ks < 2; ++ks) {
      short8 v;
#pragma unroll
      for (int j = 0; j < 8; ++j)
        v[j] = (short)f2bf(S0[(ks * 32 + kgrp * 8 + j) * HIDD + n]);
      b0[cb][ks] = v;
    }
#pragma unroll
    for (int ks = 0; ks < 4; ++ks) {
      short8 v;
#pragma unroll
      for (int j = 0; j < 8; ++j)
        v[j] = (short)f2bf(S1[(ks * 32 + kgrp * 8 + j) * HIDD + n]);
      b1[cb][ks] = v;
    }
    sh0v[cb] = sh0[d * HIDD + n];
    sh1v[cb] = sh1[d * HIDD + n];
  }
#pragma unroll
  for (int ks = 0; ks < 4; ++ks) {
    short8 v;
#pragma unroll
    for (int j = 0; j < 8; ++j)
      v[j] = (short)f2bf(S2[(ks * 32 + kgrp * 8 + j) * FEATD + lrow]);
    b2[ks] = v;
  }
  float sh2v = sh2[d * FEATD + lrow];

  for (int tile = bslot; tile * 64 < cnt; tile += BPD) {
    int base = tile * 64;

    // ---- stage X = rint(weight)/div into sX (4 threads per entry row) ----
    {
      int r = t >> 2, c = t & 3;
      int gp = base + r;
      unsigned short pe = 0;
      short8 lo = {0, 0, 0, 0, 0, 0, 0, 0}, hi = {0, 0, 0, 0, 0, 0, 0, 0};
      if (gp < cnt) {
        pe = perm[d * NN + gp];
        const float* wr = weight + (int)pe * LATD + c * 16;
        const float* dv = divv + c * 16;
#pragma unroll
        for (int q = 0; q < 2; ++q) {
          float4 f = *(const float4*)(wr + q * 4);
          float4 g = *(const float4*)(dv + q * 4);
          lo[q * 4 + 0] = (short)f2bf(rintf(f.x) / g.x);
          lo[q * 4 + 1] = (short)f2bf(rintf(f.y) / g.y);
          lo[q * 4 + 2] = (short)f2bf(rintf(f.z) / g.z);
          lo[q * 4 + 3] = (short)f2bf(rintf(f.w) / g.w);
        }
#pragma unroll
        for (int q = 0; q < 2; ++q) {
          float4 f = *(const float4*)(wr + 8 + q * 4);
          float4 g = *(const float4*)(dv + 8 + q * 4);
          hi[q * 4 + 0] = (short)f2bf(rintf(f.x) / g.x);
          hi[q * 4 + 1] = (short)f2bf(rintf(f.y) / g.y);
          hi[q * 4 + 2] = (short)f2bf(rintf(f.z) / g.z);
          hi[q * 4 + 3] = (short)f2bf(rintf(f.w) / g.w);
        }
      }
      if (c == 0) sP[r] = pe;
      *(short8*)&sX[r * SXS + c * 16] = lo;
      *(short8*)&sX[r * SXS + c * 16 + 8] = hi;
    }
    __syncthreads();

    // perm rows for this wave's L3 stores (read now: sP is stable until the
    // next tile's stage, which no wave reaches before all pass barriers 2&3)
    int prow[4];
#pragma unroll
    for (int rr = 0; rr < 4; ++rr) prow[rr] = (int)sP[w * 16 + kgrp * 4 + rr];

    // ---- layer 1: [64]->[128] relu, sX -> sH1 ----
#pragma unroll
    for (int rg = 0; rg < 4; ++rg) {
      short8 a0 = *(short8*)&sX[(rg * 16 + lrow) * SXS + kgrp * 8];
      short8 a1 = *(short8*)&sX[(rg * 16 + lrow) * SXS + 32 + kgrp * 8];
#pragma unroll
      for (int cb = 0; cb < 2; ++cb) {
        f32x4 acc = {sh0v[cb], sh0v[cb], sh0v[cb], sh0v[cb]};
        acc = __builtin_amdgcn_mfma_f32_16x16x32_bf16(a0, b0[cb][0], acc, 0, 0, 0);
        acc = __builtin_amdgcn_mfma_f32_16x16x32_bf16(a1, b0[cb][1], acc, 0, 0, 0);
#pragma unroll
        for (int rr = 0; rr < 4; ++rr)
          sH1[(rg * 16 + kgrp * 4 + rr) * SHS + (2 * w + cb) * 16 + lrow] =
              f2bf(fmaxf(acc[rr], 0.f));
      }
    }
    __syncthreads();

    // ---- layer 2: [128]->[128] relu, sH1 -> sH2 ----
#pragma unroll
    for (int rg = 0; rg < 4; ++rg) {
      short8 h0 = *(short8*)&sH1[(rg * 16 + lrow) * SHS + kgrp * 8];
      short8 h1 = *(short8*)&sH1[(rg * 16 + lrow) * SHS + 32 + kgrp * 8];
      short8 h2 = *(short8*)&sH1[(rg * 16 + lrow) * SHS + 64 + kgrp * 8];
      short8 h3 = *(short8*)&sH1[(rg * 16 + lrow) * SHS + 96 + kgrp * 8];
#pragma unroll
      for (int cb = 0; cb < 2; ++cb) {
        f32x4 acc = {sh1v[cb], sh1v[cb], sh1v[cb], sh1v[cb]};
        acc = __builtin_amdgcn_mfma_f32_16x16x32_bf16(h0, b1[cb][0], acc, 0, 0, 0);
        acc = __builtin_amdgcn_mfma_f32_16x16x32_bf16(h1, b1[cb][1], acc, 0, 0, 0);
        acc = __builtin_amdgcn_mfma_f32_16x16x32_bf16(h2, b1[cb][2], acc, 0, 0, 0);
        acc = __builtin_amdgcn_mfma_f32_16x16x32_bf16(h3, b1[cb][3], acc, 0, 0, 0);
#pragma unroll
        for (int rr = 0; rr < 4; ++rr)
          sH2[(rg * 16 + kgrp * 4 + rr) * SHS + (2 * w + cb) * 16 + lrow] =
              f2bf(fmaxf(acc[rr], 0.f));
      }
    }
    __syncthreads();

    // ---- layer 3: [128]->[16], row-group = wave, store via perm ----
    {
      short8 g0 = *(short8*)&sH2[(w * 16 + lrow) * SHS + kgrp * 8];
      short8 g1 = *(short8*)&sH2[(w * 16 + lrow) * SHS + 32 + kgrp * 8];
      short8 g2 = *(short8*)&sH2[(w * 16 + lrow) * SHS + 64 + kgrp * 8];
      short8 g3 = *(short8*)&sH2[(w * 16 + lrow) * SHS + 96 + kgrp * 8];
      f32x4 acc = {sh2v, sh2v, sh2v, sh2v};
      acc = __builtin_amdgcn_mfma_f32_16x16x32_bf16(g0, b2[0], acc, 0, 0, 0);
      acc = __builtin_amdgcn_mfma_f32_16x16x32_bf16(g1, b2[1], acc, 0, 0, 0);
      acc = __builtin_amdgcn_mfma_f32_16x16x32_bf16(g2, b2[2], acc, 0, 0, 0);
      acc = __builtin_amdgcn_mfma_f32_16x16x32_bf16(g3, b2[3], acc, 0, 0, 0);
#pragma unroll
      for (int rr = 0; rr < 4; ++rr) {
        int row = w * 16 + kgrp * 4 + rr;
        if (base + row < cnt) out[prow[rr] * FEATD + lrow] = acc[rr];
      }
    }
  }
}

// ---------------------------------------------------------------------------
extern "C" void kernel_launch(void* const* d_in, const int* in_sizes, int n_in,
                              void* d_out, int out_size, void* d_ws, size_t ws_size,
                              hipStream_t stream) {
  const float* weight      = (const float*)d_in[0];
  const float* alpha_param = (const float*)d_in[1];
  const float* divv        = (const float*)d_in[2];
  const float* scale0      = (const float*)d_in[3];
  const float* shift0      = (const float*)d_in[4];
  const float* scale1      = (const float*)d_in[5];
  const float* shift1      = (const float*)d_in[6];
  const float* scale2      = (const float*)d_in[7];
  const float* shift2      = (const float*)d_in[8];
  float* out = (float*)d_out;

  int* cursor = (int*)d_ws;                                   // [8]
  unsigned short* perm = (unsigned short*)((int*)d_ws + 8);   // [8][N]

  hipMemsetAsync(cursor, 0, DD * sizeof(int), stream);
  k_bucket<<<NN / 256, 256, 0, stream>>>(alpha_param, cursor, perm);
  k_mlp<<<DD * BPD, 256, 0, stream>>>(weight, divv,
                                      scale0, shift0, scale1, shift1,
                                      scale2, shift2,
                                      cursor, perm, out);
}